// Round 1
// baseline (1014.413 us; speedup 1.0000x reference)
//
#include <hip/hip_runtime.h>
#include <cstdint>
#include <cstddef>

// Problem constants (from reference)
#define B_    16
#define S_    1024
#define D_    768
#define NS_   256
#define MAXW_ 8
#define V_    128
#define C_    6
#define R_    512
#define REL_  97
#define HID_  384
#define DIS_  20
#define K1_   2344   // 2*(D+DIS) + D = feat width

// ---------------------------------------------------------------------------
// Kernel 1: span max-pool.  span_emb[b,n,:] = max_{j=0..w} sr[b, start+j, :]
// One block per (b,n); 256 threads, 3 elements of D each. w is block-uniform.
// ---------------------------------------------------------------------------
__global__ __launch_bounds__(256) void span_kernel(
    const float* __restrict__ sr, const int* __restrict__ spans,
    float* __restrict__ span_emb)
{
    int bn    = blockIdx.x;          // b*NS + n
    int b     = bn >> 8;             // NS = 256
    int start = spans[2 * bn];
    int end   = spans[2 * bn + 1];
    int w     = end - start;         // 0..7, always >= 0
    const float* base = sr + ((size_t)b * S_ + start) * D_;
    float* out = span_emb + (size_t)bn * D_;
    int tid = threadIdx.x;
#pragma unroll
    for (int e = 0; e < 3; ++e) {
        int d = tid + e * 256;
        float m = base[d];
        for (int j = 1; j <= w; ++j) m = fmaxf(m, base[(size_t)j * D_ + d]);
        out[d] = m;
    }
}

// ---------------------------------------------------------------------------
// Kernel 2: vertex mean.  vemb[b,v,:] = sum_c mask*span_emb[b,idx[c],:] / cnt
// One block per (b,v); 256 threads, 3 elements each.
// ---------------------------------------------------------------------------
__global__ __launch_bounds__(256) void vertex_kernel(
    const float* __restrict__ span_emb, const int* __restrict__ vidx,
    const int* __restrict__ vmask, float* __restrict__ vemb)
{
    int bv = blockIdx.x;             // b*V + v
    int b  = bv >> 7;                // V = 128
    const int* vi = vidx  + bv * C_;
    const int* vm = vmask + bv * C_;
    int   idxs[C_];
    float ms[C_];
    float cnt = 0.f;
#pragma unroll
    for (int c = 0; c < C_; ++c) {
        idxs[c] = vi[c];
        ms[c]   = (float)vm[c];
        cnt    += ms[c];
    }
    float inv = 1.f / fmaxf(cnt, 1.f);
    int tid = threadIdx.x;
    float* out = vemb + (size_t)bv * D_;
#pragma unroll
    for (int e = 0; e < 3; ++e) {
        int d = tid + e * 256;
        float s = 0.f;
#pragma unroll
        for (int c = 0; c < C_; ++c) {
            if (ms[c] != 0.f)
                s += span_emb[((size_t)(b * NS_ + idxs[c])) * D_ + d];
        }
        out[d] = s * inv;
    }
}

// ---------------------------------------------------------------------------
// Kernel 3: fused-gather GEMM1 + ReLU.
// hidden[r, n] = relu( sum_k feat(r,k) * W1[k,n] )
// feat(r,k) built on-the-fly in A-tile staging:
//   [0,768)      head = vemb[b*V + ht0]
//   [768,788)    dis_embed[dis_h_2_t[r]]
//   [788,1556)   tail = vemb[b*V + ht1]
//   [1556,1576)  dis_embed[dis_t_2_h[r]]
//   [1576,2344)  head * tail
// 64x64 output tile, K-chunk 32, 4x4 per-thread register block.
// ---------------------------------------------------------------------------
__global__ __launch_bounds__(256) void gemm1_kernel(
    const float* __restrict__ vemb, const int* __restrict__ ht,
    const int* __restrict__ dht, const int* __restrict__ dth,
    const float* __restrict__ dis, const float* __restrict__ W1,
    float* __restrict__ hidden)
{
    __shared__ float As[64][33];   // +1 pad: staging writes 2-way, reads broadcast
    __shared__ float Bs[32][68];   // +4 pad: rows 272B -> 16B aligned for b128 reads
    __shared__ int rh[64], rt[64], rdh[64], rdt[64];

    int m0  = blockIdx.x * 64;
    int n0  = blockIdx.y * 64;
    int tid = threadIdx.x;

    if (tid < 64) {
        int r = m0 + tid;            // global row = b*R + rel
        int b = r >> 9;              // R = 512
        rh[tid]  = b * V_ + ht[2 * r];
        rt[tid]  = b * V_ + ht[2 * r + 1];
        rdh[tid] = dht[r];
        rdt[tid] = dth[r];
    }
    __syncthreads();

    int tx = tid & 15;               // col quad -> cols n0 + tx*4 .. +3
    int ty = tid >> 4;               // row quad -> rows m0 + ty*4 .. +3
    float acc[4][4];
#pragma unroll
    for (int i = 0; i < 4; ++i)
#pragma unroll
        for (int j = 0; j < 4; ++j) acc[i][j] = 0.f;

    for (int k0 = 0; k0 < K1_; k0 += 32) {
        // Stage A tile: 64 rows x 32 k = 2048 elems, 8 per thread.
        // Consecutive lanes -> consecutive k of one row -> coalesced vemb reads.
#pragma unroll
        for (int e = 0; e < 8; ++e) {
            int idx = tid + e * 256;
            int i   = idx >> 5;
            int kk  = idx & 31;
            int k   = k0 + kk;
            float v;
            if (k < D_) {
                v = vemb[(size_t)rh[i] * D_ + k];
            } else if (k < D_ + DIS_) {
                v = dis[rdh[i] * DIS_ + (k - D_)];
            } else if (k < 2 * D_ + DIS_) {
                v = vemb[(size_t)rt[i] * D_ + (k - (D_ + DIS_))];
            } else if (k < 2 * D_ + 2 * DIS_) {
                v = dis[rdt[i] * DIS_ + (k - (2 * D_ + DIS_))];
            } else if (k < K1_) {
                int kd = k - (2 * D_ + 2 * DIS_);
                v = vemb[(size_t)rh[i] * D_ + kd] * vemb[(size_t)rt[i] * D_ + kd];
            } else {
                v = 0.f;             // K tail (2344 = 73*32 + 8)
            }
            As[i][kk] = v;
        }
        // Stage B tile: 32 k x 64 n = 2048 elems, 8 per thread, coalesced.
#pragma unroll
        for (int e = 0; e < 8; ++e) {
            int idx = tid + e * 256;
            int kk  = idx >> 6;
            int nn  = idx & 63;
            int k   = k0 + kk;
            Bs[kk][nn] = (k < K1_) ? W1[(size_t)k * HID_ + n0 + nn] : 0.f;
        }
        __syncthreads();
#pragma unroll
        for (int kk = 0; kk < 32; ++kk) {
            float a[4], bb[4];
#pragma unroll
            for (int i = 0; i < 4; ++i) a[i] = As[ty * 4 + i][kk];
#pragma unroll
            for (int j = 0; j < 4; ++j) bb[j] = Bs[kk][tx * 4 + j];
#pragma unroll
            for (int i = 0; i < 4; ++i)
#pragma unroll
                for (int j = 0; j < 4; ++j)
                    acc[i][j] = fmaf(a[i], bb[j], acc[i][j]);
        }
        __syncthreads();
    }

#pragma unroll
    for (int i = 0; i < 4; ++i) {
        int r = m0 + ty * 4 + i;
        float* o = hidden + (size_t)r * HID_ + n0 + tx * 4;
#pragma unroll
        for (int j = 0; j < 4; ++j) o[j] = fmaxf(acc[i][j], 0.f);  // fused ReLU
    }
}

// ---------------------------------------------------------------------------
// Kernel 4: GEMM2 + bias.  out[r, c] = hidden[r,:] @ W2[:, c] + b2[c]
// 32x128 tile (cols masked to 97), K-chunk 32, 4x4 per-thread block.
// ---------------------------------------------------------------------------
__global__ __launch_bounds__(256) void gemm2_kernel(
    const float* __restrict__ hidden, const float* __restrict__ W2,
    const float* __restrict__ b2, float* __restrict__ out)
{
    __shared__ float As[32][33];
    __shared__ float Bs[32][132];  // 128 + 4 pad -> 528B rows, 16B aligned

    int m0  = blockIdx.x * 32;
    int tid = threadIdx.x;
    int tx  = tid & 31;            // col quad -> cols tx*4 .. +3 (0..127)
    int ty  = tid >> 5;            // 0..7 -> rows ty*4 .. +3

    float acc[4][4];
#pragma unroll
    for (int i = 0; i < 4; ++i)
#pragma unroll
        for (int j = 0; j < 4; ++j) acc[i][j] = 0.f;

    for (int k0 = 0; k0 < HID_; k0 += 32) {
        // A: 32 rows x 32 k = 1024 elems, 4 per thread, coalesced
#pragma unroll
        for (int e = 0; e < 4; ++e) {
            int idx = tid + e * 256;
            int i   = idx >> 5;
            int kk  = idx & 31;
            As[i][kk] = hidden[(size_t)(m0 + i) * HID_ + k0 + kk];
        }
        // B: 32 k x 128 n = 4096 elems, 16 per thread; mask n >= 97
#pragma unroll
        for (int e = 0; e < 16; ++e) {
            int idx = tid + e * 256;
            int kk  = idx >> 7;
            int nn  = idx & 127;
            Bs[kk][nn] = (nn < REL_) ? W2[(size_t)(k0 + kk) * REL_ + nn] : 0.f;
        }
        __syncthreads();
#pragma unroll
        for (int kk = 0; kk < 32; ++kk) {
            float a[4], bb[4];
#pragma unroll
            for (int i = 0; i < 4; ++i) a[i] = As[ty * 4 + i][kk];
#pragma unroll
            for (int j = 0; j < 4; ++j) bb[j] = Bs[kk][tx * 4 + j];
#pragma unroll
            for (int i = 0; i < 4; ++i)
#pragma unroll
                for (int j = 0; j < 4; ++j)
                    acc[i][j] = fmaf(a[i], bb[j], acc[i][j]);
        }
        __syncthreads();
    }

#pragma unroll
    for (int i = 0; i < 4; ++i) {
        int r = m0 + ty * 4 + i;
#pragma unroll
        for (int j = 0; j < 4; ++j) {
            int c = tx * 4 + j;
            if (c < REL_) out[(size_t)r * REL_ + c] = acc[i][j] + b2[c];
        }
    }
}

// ---------------------------------------------------------------------------
extern "C" void kernel_launch(void* const* d_in, const int* in_sizes, int n_in,
                              void* d_out, int out_size, void* d_ws, size_t ws_size,
                              hipStream_t stream)
{
    const float* sr    = (const float*)d_in[0];   // (B,S,D)
    const int*   spans = (const int*)  d_in[1];   // (B,NS,2)
    // d_in[2] entity_span_indices_mask: UNUSED by reference
    const int*   vidx  = (const int*)  d_in[3];   // (B,V,C)
    const int*   vmask = (const int*)  d_in[4];   // (B,V,C)
    const int*   ht    = (const int*)  d_in[5];   // (B,R,2)
    // d_in[6] relation_mask: UNUSED by reference
    const int*   dht   = (const int*)  d_in[7];   // (B,R)
    const int*   dth   = (const int*)  d_in[8];   // (B,R)
    const float* dis   = (const float*)d_in[9];   // (20,20)
    const float* W1    = (const float*)d_in[10];  // (2344,384)
    const float* W2    = (const float*)d_in[11];  // (384,97)
    const float* b2    = (const float*)d_in[12];  // (97,)
    float* out = (float*)d_out;                   // (B,R,97) fp32

    // Workspace layout (fp32): span_emb | vemb | hidden  = ~31.5 MB total
    float* span_emb = (float*)d_ws;                       // 4096*768
    float* vemb     = span_emb + (size_t)B_ * NS_ * D_;   // 2048*768
    float* hidden   = vemb     + (size_t)B_ * V_  * D_;   // 8192*384

    span_kernel<<<B_ * NS_, 256, 0, stream>>>(sr, spans, span_emb);
    vertex_kernel<<<B_ * V_, 256, 0, stream>>>(span_emb, vidx, vmask, vemb);

    dim3 g1((B_ * R_) / 64, HID_ / 64);                   // 128 x 6
    gemm1_kernel<<<g1, 256, 0, stream>>>(vemb, ht, dht, dth, dis, W1, hidden);

    gemm2_kernel<<<(B_ * R_) / 32, 256, 0, stream>>>(hidden, W2, b2, out);
}

// Round 2
// 230.319 us; speedup vs baseline: 4.4044x; 4.4044x over previous
//
#include <hip/hip_runtime.h>
#include <cstdint>
#include <cstddef>

// Problem constants
#define B_    16
#define S_    1024
#define D_    768
#define NS_   256
#define V_    128
#define C_    6
#define R_    512
#define REL_  97
#define HID_  384
#define DIS_  20
#define K1_   2344   // true feat width
#define KP_   2368   // permuted+padded K (74*32 = 37*64)

typedef unsigned short ushort_t;
typedef short bf16x8 __attribute__((ext_vector_type(8)));
typedef float f32x4  __attribute__((ext_vector_type(4)));

__device__ __forceinline__ float bf2f(short s) {
    return __uint_as_float(((unsigned int)(unsigned short)s) << 16);
}
__device__ __forceinline__ short f2bf(float x) {   // RNE
    union { float f; unsigned int u; } c; c.f = x;
    unsigned int r = (c.u + 0x7fffu + ((c.u >> 16) & 1u)) >> 16;
    return (short)(unsigned short)r;
}

// ---------------------------------------------------------------------------
// Kernel 1: span max-pool (fp32 out).
// ---------------------------------------------------------------------------
__global__ __launch_bounds__(256) void span_kernel(
    const float* __restrict__ sr, const int* __restrict__ spans,
    float* __restrict__ span_emb)
{
    int bn    = blockIdx.x;
    int b     = bn >> 8;             // NS = 256
    int start = spans[2 * bn];
    int end   = spans[2 * bn + 1];
    int w     = end - start;         // 0..7
    const float* base = sr + ((size_t)b * S_ + start) * D_;
    float* out = span_emb + (size_t)bn * D_;
    int tid = threadIdx.x;
#pragma unroll
    for (int e = 0; e < 3; ++e) {
        int d = tid + e * 256;
        float m = base[d];
        for (int j = 1; j <= w; ++j) m = fmaxf(m, base[(size_t)j * D_ + d]);
        out[d] = m;
    }
}

// ---------------------------------------------------------------------------
// Kernel 2: vertex mean -> bf16 output (MFMA A-operand source).
// ---------------------------------------------------------------------------
__global__ __launch_bounds__(256) void vertex_kernel(
    const float* __restrict__ span_emb, const int* __restrict__ vidx,
    const int* __restrict__ vmask, ushort_t* __restrict__ vembB)
{
    int bv = blockIdx.x;
    int b  = bv >> 7;                // V = 128
    const int* vi = vidx  + bv * C_;
    const int* vm = vmask + bv * C_;
    int   idxs[C_];
    float ms[C_];
    float cnt = 0.f;
#pragma unroll
    for (int c = 0; c < C_; ++c) {
        idxs[c] = vi[c];
        ms[c]   = (float)vm[c];
        cnt    += ms[c];
    }
    float inv = 1.f / fmaxf(cnt, 1.f);
    int tid = threadIdx.x;
    ushort_t* out = vembB + (size_t)bv * D_;
#pragma unroll
    for (int e = 0; e < 3; ++e) {
        int d = tid + e * 256;
        float s = 0.f;
#pragma unroll
        for (int c = 0; c < C_; ++c) {
            if (ms[c] != 0.f)
                s += span_emb[((size_t)(b * NS_ + idxs[c])) * D_ + d];
        }
        out[d] = (ushort_t)f2bf(s * inv);
    }
}

// ---------------------------------------------------------------------------
// Kernel 2b: W1 (2344x384 fp32) -> W1T (384 x KP bf16), K permuted:
//   k' < 768        : head          (orig k')
//   768  <= k'<1536 : tail          (orig k'+20)
//   1536 <= k'<2304 : head*tail     (orig k'+40)
//   2304 <= k'<2324 : dis_h         (orig 768 + (k'-2304))
//   2324 <= k'<2344 : dis_t         (orig 1556 + (k'-2324))
//   k' >= 2344      : zero pad
// ---------------------------------------------------------------------------
__global__ __launch_bounds__(256) void w1_convert_kernel(
    const float* __restrict__ W1, ushort_t* __restrict__ W1T)
{
    int n = blockIdx.x;              // 0..383
    for (int k = threadIdx.x; k < KP_; k += 256) {
        int orig;
        if      (k < 768)  orig = k;
        else if (k < 1536) orig = k + 20;
        else if (k < 2304) orig = k + 40;
        else if (k < 2324) orig = 768 + (k - 2304);
        else if (k < K1_)  orig = 1556 + (k - 2324);
        else               orig = -1;
        float v = (orig >= 0) ? W1[(size_t)orig * HID_ + n] : 0.f;
        W1T[(size_t)n * KP_ + k] = (ushort_t)f2bf(v);
    }
}

// ---------------------------------------------------------------------------
// Kernel 3: fused-gather MFMA GEMM1 + ReLU.
// hidden(8192x384) = relu( feat'(8192 x KP) @ W1T^T )
// 64x64 tile, BK=64, 4 waves of 32x32, 16x16x32 bf16 MFMA, prefetch pipeline.
// ---------------------------------------------------------------------------
__global__ __launch_bounds__(256) void gemm1_kernel(
    const ushort_t* __restrict__ vembB, const int* __restrict__ ht,
    const int* __restrict__ dht, const int* __restrict__ dth,
    const float* __restrict__ dis, const ushort_t* __restrict__ W1T,
    float* __restrict__ hidden)
{
    // rows padded 64->72 bf16 (144 B = 36 banks, 16B-aligned) -> conflict-light
    __shared__ ushort_t As[64][72];
    __shared__ ushort_t Bs[64][72];

    int m0  = blockIdx.x * 64;       // 128 m-tiles
    int n0  = blockIdx.y * 64;       // 6 n-tiles
    int tid = threadIdx.x;

    // ---- staging assignment: thread -> rows (r, r+32), k-chunk of 8
    int arow0 = tid >> 3;            // 0..31
    int akk   = (tid & 7) * 8;       // 0,8,..,56

    // per-thread row indices (fixed across K loop)
    int g0 = m0 + arow0, g1 = g0 + 32;
    int b0 = g0 >> 9,    b1 = g1 >> 9;           // R = 512
    int rh0 = b0 * V_ + ht[2 * g0], rt0 = b0 * V_ + ht[2 * g0 + 1];
    int rh1 = b1 * V_ + ht[2 * g1], rt1 = b1 * V_ + ht[2 * g1 + 1];
    int rdh0 = dht[g0], rdt0 = dth[g0];
    int rdh1 = dht[g1], rdt1 = dth[g1];

    auto stageA = [&](int kk0, int rh_, int rt_, int rdh_, int rdt_) -> bf16x8 {
        int kg = kk0 + akk;
        if (kk0 < 768) {
            return *(const bf16x8*)(vembB + (size_t)rh_ * D_ + kg);
        } else if (kk0 < 1536) {
            return *(const bf16x8*)(vembB + (size_t)rt_ * D_ + (kg - 768));
        } else if (kk0 < 2304) {
            int kd = kg - 1536;
            bf16x8 h = *(const bf16x8*)(vembB + (size_t)rh_ * D_ + kd);
            bf16x8 t = *(const bf16x8*)(vembB + (size_t)rt_ * D_ + kd);
            bf16x8 p;
#pragma unroll
            for (int j = 0; j < 8; ++j) p[j] = f2bf(bf2f(h[j]) * bf2f(t[j]));
            return p;
        } else {
            bf16x8 p;
#pragma unroll
            for (int j = 0; j < 8; ++j) {
                int kglob = kg + j;
                float v = 0.f;
                if      (kglob < 2324) v = dis[rdh_ * DIS_ + (kglob - 2304)];
                else if (kglob < K1_)  v = dis[rdt_ * DIS_ + (kglob - 2324)];
                p[j] = f2bf(v);
            }
            return p;
        }
    };

    bf16x8 pA0, pA1, pB0, pB1;
    auto loadAB = [&](int kk0) {
        pA0 = stageA(kk0, rh0, rt0, rdh0, rdt0);
        pA1 = stageA(kk0, rh1, rt1, rdh1, rdt1);
        pB0 = *(const bf16x8*)(W1T + (size_t)(n0 + arow0)      * KP_ + kk0 + akk);
        pB1 = *(const bf16x8*)(W1T + (size_t)(n0 + arow0 + 32) * KP_ + kk0 + akk);
    };

    // ---- compute assignment: 4 waves, 2x2, each 32x32
    int w    = tid >> 6;
    int lane = tid & 63;
    int wm = (w & 1) * 32, wn = (w >> 1) * 32;
    int lr = lane & 15, lq = lane >> 4;

    f32x4 acc00 = {0.f, 0.f, 0.f, 0.f};
    f32x4 acc01 = acc00, acc10 = acc00, acc11 = acc00;

    loadAB(0);
    for (int k0 = 0; k0 < KP_; k0 += 64) {
        __syncthreads();                       // prior reads done
        *(bf16x8*)&As[arow0][akk]      = pA0;
        *(bf16x8*)&As[arow0 + 32][akk] = pA1;
        *(bf16x8*)&Bs[arow0][akk]      = pB0;
        *(bf16x8*)&Bs[arow0 + 32][akk] = pB1;
        __syncthreads();
        if (k0 + 64 < KP_) loadAB(k0 + 64);    // prefetch overlaps MFMA
#pragma unroll
        for (int ks = 0; ks < 2; ++ks) {
            int kb = ks * 32 + lq * 8;
            bf16x8 a0 = *(bf16x8*)&As[wm + lr][kb];
            bf16x8 a1 = *(bf16x8*)&As[wm + 16 + lr][kb];
            bf16x8 bb0 = *(bf16x8*)&Bs[wn + lr][kb];
            bf16x8 bb1 = *(bf16x8*)&Bs[wn + 16 + lr][kb];
            acc00 = __builtin_amdgcn_mfma_f32_16x16x32_bf16(a0, bb0, acc00, 0, 0, 0);
            acc01 = __builtin_amdgcn_mfma_f32_16x16x32_bf16(a0, bb1, acc01, 0, 0, 0);
            acc10 = __builtin_amdgcn_mfma_f32_16x16x32_bf16(a1, bb0, acc10, 0, 0, 0);
            acc11 = __builtin_amdgcn_mfma_f32_16x16x32_bf16(a1, bb1, acc11, 0, 0, 0);
        }
    }

    // ---- epilogue: C/D layout row=(lane>>4)*4+r, col=lane&15; fused ReLU
    int grow = m0 + wm + lq * 4;
    int gcol = n0 + wn + lr;
    auto st = [&](f32x4 v, int rr, int cc) {
#pragma unroll
        for (int r = 0; r < 4; ++r)
            hidden[(size_t)(rr + r) * HID_ + cc] = fmaxf(v[r], 0.f);
    };
    st(acc00, grow,      gcol);
    st(acc01, grow,      gcol + 16);
    st(acc10, grow + 16, gcol);
    st(acc11, grow + 16, gcol + 16);
}

// ---------------------------------------------------------------------------
// Kernel 4: GEMM2 + bias (fp32 VALU).
// ---------------------------------------------------------------------------
__global__ __launch_bounds__(256) void gemm2_kernel(
    const float* __restrict__ hidden, const float* __restrict__ W2,
    const float* __restrict__ b2, float* __restrict__ out)
{
    __shared__ float As[32][33];
    __shared__ float Bs[32][132];

    int m0  = blockIdx.x * 32;
    int tid = threadIdx.x;
    int tx  = tid & 31;
    int ty  = tid >> 5;

    float acc[4][4];
#pragma unroll
    for (int i = 0; i < 4; ++i)
#pragma unroll
        for (int j = 0; j < 4; ++j) acc[i][j] = 0.f;

    for (int k0 = 0; k0 < HID_; k0 += 32) {
#pragma unroll
        for (int e = 0; e < 4; ++e) {
            int idx = tid + e * 256;
            int i   = idx >> 5;
            int kk  = idx & 31;
            As[i][kk] = hidden[(size_t)(m0 + i) * HID_ + k0 + kk];
        }
#pragma unroll
        for (int e = 0; e < 16; ++e) {
            int idx = tid + e * 256;
            int kk  = idx >> 7;
            int nn  = idx & 127;
            Bs[kk][nn] = (nn < REL_) ? W2[(size_t)(k0 + kk) * REL_ + nn] : 0.f;
        }
        __syncthreads();
#pragma unroll
        for (int kk = 0; kk < 32; ++kk) {
            float a[4], bb[4];
#pragma unroll
            for (int i = 0; i < 4; ++i) a[i] = As[ty * 4 + i][kk];
#pragma unroll
            for (int j = 0; j < 4; ++j) bb[j] = Bs[kk][tx * 4 + j];
#pragma unroll
            for (int i = 0; i < 4; ++i)
#pragma unroll
                for (int j = 0; j < 4; ++j)
                    acc[i][j] = fmaf(a[i], bb[j], acc[i][j]);
        }
        __syncthreads();
    }

#pragma unroll
    for (int i = 0; i < 4; ++i) {
        int r = m0 + ty * 4 + i;
#pragma unroll
        for (int j = 0; j < 4; ++j) {
            int c = tx * 4 + j;
            if (c < REL_) out[(size_t)r * REL_ + c] = acc[i][j] + b2[c];
        }
    }
}

// ---------------------------------------------------------------------------
extern "C" void kernel_launch(void* const* d_in, const int* in_sizes, int n_in,
                              void* d_out, int out_size, void* d_ws, size_t ws_size,
                              hipStream_t stream)
{
    const float* sr    = (const float*)d_in[0];
    const int*   spans = (const int*)  d_in[1];
    const int*   vidx  = (const int*)  d_in[3];
    const int*   vmask = (const int*)  d_in[4];
    const int*   ht    = (const int*)  d_in[5];
    const int*   dht   = (const int*)  d_in[7];
    const int*   dth   = (const int*)  d_in[8];
    const float* dis   = (const float*)d_in[9];
    const float* W1    = (const float*)d_in[10];
    const float* W2    = (const float*)d_in[11];
    const float* b2    = (const float*)d_in[12];
    float* out = (float*)d_out;

    // ws layout: span_emb fp32 | vembB bf16 | W1T bf16 | hidden fp32 (~30 MB)
    float*    span_emb = (float*)d_ws;                                 // 4096*768 f32
    ushort_t* vembB    = (ushort_t*)(span_emb + (size_t)B_ * NS_ * D_);// 2048*768 bf16
    ushort_t* W1T      = vembB + (size_t)B_ * V_ * D_;                 // 384*2368 bf16
    float*    hidden   = (float*)(W1T + (size_t)HID_ * KP_);           // 8192*384 f32

    span_kernel<<<B_ * NS_, 256, 0, stream>>>(sr, spans, span_emb);
    vertex_kernel<<<B_ * V_, 256, 0, stream>>>(span_emb, vidx, vmask, vembB);
    w1_convert_kernel<<<HID_, 256, 0, stream>>>(W1, W1T);

    dim3 g1((B_ * R_) / 64, HID_ / 64);        // 128 x 6 = 768 blocks
    gemm1_kernel<<<g1, 256, 0, stream>>>(vembB, ht, dht, dth, dis, W1T, hidden);

    gemm2_kernel<<<(B_ * R_) / 32, 256, 0, stream>>>(hidden, W2, b2, out);
}

// Round 3
// 177.559 us; speedup vs baseline: 5.7131x; 1.2971x over previous
//
#include <hip/hip_runtime.h>
#include <cstdint>
#include <cstddef>

// Problem constants
#define B_    16
#define S_    1024
#define D_    768
#define NS_   256
#define V_    128
#define C_    6
#define R_    512
#define REL_  97
#define HID_  384
#define DIS_  20
#define K1_   2344   // true feat width
#define KP_   2368   // permuted+padded K (74*32 = 37*64)
#define N2P_  128    // gemm2 padded N

typedef unsigned short ushort_t;
typedef short bf16x8 __attribute__((ext_vector_type(8)));
typedef float f32x4  __attribute__((ext_vector_type(4)));

__device__ __forceinline__ float bf2f(short s) {
    return __uint_as_float(((unsigned int)(unsigned short)s) << 16);
}
__device__ __forceinline__ short f2bf(float x) {   // RNE
    union { float f; unsigned int u; } c; c.f = x;
    unsigned int r = (c.u + 0x7fffu + ((c.u >> 16) & 1u)) >> 16;
    return (short)(unsigned short)r;
}

// ---------------------------------------------------------------------------
// Kernel 1: span max-pool (fp32 out).
// ---------------------------------------------------------------------------
__global__ __launch_bounds__(256) void span_kernel(
    const float* __restrict__ sr, const int* __restrict__ spans,
    float* __restrict__ span_emb)
{
    int bn    = blockIdx.x;
    int b     = bn >> 8;             // NS = 256
    int start = spans[2 * bn];
    int end   = spans[2 * bn + 1];
    int w     = end - start;         // 0..7
    const float* base = sr + ((size_t)b * S_ + start) * D_;
    float* out = span_emb + (size_t)bn * D_;
    int tid = threadIdx.x;
#pragma unroll
    for (int e = 0; e < 3; ++e) {
        int d = tid + e * 256;
        float m = base[d];
        for (int j = 1; j <= w; ++j) m = fmaxf(m, base[(size_t)j * D_ + d]);
        out[d] = m;
    }
}

// ---------------------------------------------------------------------------
// Kernel 2: vertex mean -> bf16 output (MFMA A-operand source).
// ---------------------------------------------------------------------------
__global__ __launch_bounds__(256) void vertex_kernel(
    const float* __restrict__ span_emb, const int* __restrict__ vidx,
    const int* __restrict__ vmask, ushort_t* __restrict__ vembB)
{
    int bv = blockIdx.x;
    int b  = bv >> 7;                // V = 128
    const int* vi = vidx  + bv * C_;
    const int* vm = vmask + bv * C_;
    int   idxs[C_];
    float ms[C_];
    float cnt = 0.f;
#pragma unroll
    for (int c = 0; c < C_; ++c) {
        idxs[c] = vi[c];
        ms[c]   = (float)vm[c];
        cnt    += ms[c];
    }
    float inv = 1.f / fmaxf(cnt, 1.f);
    int tid = threadIdx.x;
    ushort_t* out = vembB + (size_t)bv * D_;
#pragma unroll
    for (int e = 0; e < 3; ++e) {
        int d = tid + e * 256;
        float s = 0.f;
#pragma unroll
        for (int c = 0; c < C_; ++c) {
            if (ms[c] != 0.f)
                s += span_emb[((size_t)(b * NS_ + idxs[c])) * D_ + d];
        }
        out[d] = (ushort_t)f2bf(s * inv);
    }
}

// ---------------------------------------------------------------------------
// Kernel 2b: weight conversion (coalesced transpose pattern).
//  Blocks [0,148): W1 (2344x384 f32) -> W1T (384 x KP bf16), K permuted:
//    k' < 768        : head       (orig k')
//    768  <= k'<1536 : tail       (orig k'+20)
//    1536 <= k'<2304 : head*tail  (orig k'+40)
//    2304 <= k'<2324 : dis_h      (orig 768 + (k'-2304))
//    2324 <= k'<2344 : dis_t      (orig 1556 + (k'-2324))
//    k' >= 2344      : zero pad
//  Reads coalesced across n (=tid), writes per-thread contiguous k.
//  Blocks [148,156): W2 (384x97 f32) -> W2T (128 x 384 bf16), n-padded.
// ---------------------------------------------------------------------------
__global__ __launch_bounds__(384) void wconv_kernel(
    const float* __restrict__ W1, const float* __restrict__ W2,
    ushort_t* __restrict__ W1T, ushort_t* __restrict__ W2T)
{
    int tid = threadIdx.x;
    if (blockIdx.x < 148) {
        int k0 = blockIdx.x * 16;
        int n  = tid;                        // 0..383
#pragma unroll
        for (int i = 0; i < 16; ++i) {
            int k = k0 + i;
            int orig;
            if      (k < 768)  orig = k;
            else if (k < 1536) orig = k + 20;
            else if (k < 2304) orig = k + 40;
            else if (k < 2324) orig = 768 + (k - 2304);
            else if (k < K1_)  orig = 1556 + (k - 2324);
            else               orig = -1;
            float v = (orig >= 0) ? W1[(size_t)orig * HID_ + n] : 0.f;
            W1T[(size_t)n * KP_ + k] = (ushort_t)f2bf(v);
        }
    } else {
        int bid = blockIdx.x - 148;          // 0..7
#pragma unroll
        for (int i = 0; i < 16; ++i) {
            int e = bid * 6144 + tid + i * 384;   // 8*6144 = 49152 = 128*384
            int n = e / HID_;
            int k = e - n * HID_;
            float v = (n < REL_) ? W2[(size_t)k * REL_ + n] : 0.f;
            W2T[e] = (ushort_t)f2bf(v);
        }
    }
}

// ---------------------------------------------------------------------------
// Kernel 3: fused-gather MFMA GEMM1 + ReLU -> bf16 hidden.
// 64x64 tile, BK=64, 4 waves of 32x32, 16x16x32 bf16 MFMA, prefetch pipeline.
// ---------------------------------------------------------------------------
__global__ __launch_bounds__(256) void gemm1_kernel(
    const ushort_t* __restrict__ vembB, const int* __restrict__ ht,
    const int* __restrict__ dht, const int* __restrict__ dth,
    const float* __restrict__ dis, const ushort_t* __restrict__ W1T,
    ushort_t* __restrict__ hiddenB)
{
    __shared__ ushort_t As[64][72];   // 144 B rows: 16B-aligned, pow2-broken
    __shared__ ushort_t Bs[64][72];

    int m0  = blockIdx.x * 64;
    int n0  = blockIdx.y * 64;
    int tid = threadIdx.x;

    int arow0 = tid >> 3;            // 0..31
    int akk   = (tid & 7) * 8;       // 0,8,..,56

    int g0 = m0 + arow0, g1 = g0 + 32;
    int b0 = g0 >> 9,    b1 = g1 >> 9;           // R = 512
    int rh0 = b0 * V_ + ht[2 * g0], rt0 = b0 * V_ + ht[2 * g0 + 1];
    int rh1 = b1 * V_ + ht[2 * g1], rt1 = b1 * V_ + ht[2 * g1 + 1];
    int rdh0 = dht[g0], rdt0 = dth[g0];
    int rdh1 = dht[g1], rdt1 = dth[g1];

    auto stageA = [&](int kk0, int rh_, int rt_, int rdh_, int rdt_) -> bf16x8 {
        int kg = kk0 + akk;
        if (kk0 < 768) {
            return *(const bf16x8*)(vembB + (size_t)rh_ * D_ + kg);
        } else if (kk0 < 1536) {
            return *(const bf16x8*)(vembB + (size_t)rt_ * D_ + (kg - 768));
        } else if (kk0 < 2304) {
            int kd = kg - 1536;
            bf16x8 h = *(const bf16x8*)(vembB + (size_t)rh_ * D_ + kd);
            bf16x8 t = *(const bf16x8*)(vembB + (size_t)rt_ * D_ + kd);
            bf16x8 p;
#pragma unroll
            for (int j = 0; j < 8; ++j) p[j] = f2bf(bf2f(h[j]) * bf2f(t[j]));
            return p;
        } else {
            bf16x8 p;
#pragma unroll
            for (int j = 0; j < 8; ++j) {
                int kglob = kg + j;
                float v = 0.f;
                if      (kglob < 2324) v = dis[rdh_ * DIS_ + (kglob - 2304)];
                else if (kglob < K1_)  v = dis[rdt_ * DIS_ + (kglob - 2324)];
                p[j] = f2bf(v);
            }
            return p;
        }
    };

    bf16x8 pA0, pA1, pB0, pB1;
    auto loadAB = [&](int kk0) {
        pA0 = stageA(kk0, rh0, rt0, rdh0, rdt0);
        pA1 = stageA(kk0, rh1, rt1, rdh1, rdt1);
        pB0 = *(const bf16x8*)(W1T + (size_t)(n0 + arow0)      * KP_ + kk0 + akk);
        pB1 = *(const bf16x8*)(W1T + (size_t)(n0 + arow0 + 32) * KP_ + kk0 + akk);
    };

    int w    = tid >> 6;
    int lane = tid & 63;
    int wm = (w & 1) * 32, wn = (w >> 1) * 32;
    int lr = lane & 15, lq = lane >> 4;

    f32x4 acc00 = {0.f, 0.f, 0.f, 0.f};
    f32x4 acc01 = acc00, acc10 = acc00, acc11 = acc00;

    loadAB(0);
    for (int k0 = 0; k0 < KP_; k0 += 64) {
        __syncthreads();
        *(bf16x8*)&As[arow0][akk]      = pA0;
        *(bf16x8*)&As[arow0 + 32][akk] = pA1;
        *(bf16x8*)&Bs[arow0][akk]      = pB0;
        *(bf16x8*)&Bs[arow0 + 32][akk] = pB1;
        __syncthreads();
        if (k0 + 64 < KP_) loadAB(k0 + 64);
#pragma unroll
        for (int ks = 0; ks < 2; ++ks) {
            int kb = ks * 32 + lq * 8;
            bf16x8 a0 = *(bf16x8*)&As[wm + lr][kb];
            bf16x8 a1 = *(bf16x8*)&As[wm + 16 + lr][kb];
            bf16x8 bb0 = *(bf16x8*)&Bs[wn + lr][kb];
            bf16x8 bb1 = *(bf16x8*)&Bs[wn + 16 + lr][kb];
            acc00 = __builtin_amdgcn_mfma_f32_16x16x32_bf16(a0, bb0, acc00, 0, 0, 0);
            acc01 = __builtin_amdgcn_mfma_f32_16x16x32_bf16(a0, bb1, acc01, 0, 0, 0);
            acc10 = __builtin_amdgcn_mfma_f32_16x16x32_bf16(a1, bb0, acc10, 0, 0, 0);
            acc11 = __builtin_amdgcn_mfma_f32_16x16x32_bf16(a1, bb1, acc11, 0, 0, 0);
        }
    }

    // epilogue: row=(lane>>4)*4+r, col=lane&15; fused ReLU; bf16 store
    int grow = m0 + wm + lq * 4;
    int gcol = n0 + wn + lr;
    auto st = [&](f32x4 v, int rr, int cc) {
#pragma unroll
        for (int r = 0; r < 4; ++r)
            hiddenB[(size_t)(rr + r) * HID_ + cc] =
                (ushort_t)f2bf(fmaxf(v[r], 0.f));
    };
    st(acc00, grow,      gcol);
    st(acc01, grow,      gcol + 16);
    st(acc10, grow + 16, gcol);
    st(acc11, grow + 16, gcol + 16);
}

// ---------------------------------------------------------------------------
// Kernel 4: MFMA GEMM2 + bias.  out(8192x97) = hiddenB @ W2T^T + b2
// 32x128 tile, BK=64, 4 waves each 16 rows x 64 cols, prefetch pipeline.
// ---------------------------------------------------------------------------
__global__ __launch_bounds__(256) void gemm2_kernel(
    const ushort_t* __restrict__ hiddenB, const ushort_t* __restrict__ W2T,
    const float* __restrict__ b2, float* __restrict__ out)
{
    __shared__ ushort_t As[32][72];
    __shared__ ushort_t Bs[128][72];

    int m0  = blockIdx.x * 32;
    int tid = threadIdx.x;

    int arow = tid >> 3;             // 0..31
    int akk  = (tid & 7) * 8;

    bf16x8 pA, pB[4];
    auto loadAB = [&](int k0) {
        pA = *(const bf16x8*)(hiddenB + (size_t)(m0 + arow) * HID_ + k0 + akk);
#pragma unroll
        for (int e = 0; e < 4; ++e)
            pB[e] = *(const bf16x8*)(W2T + (size_t)(arow + e * 32) * HID_ + k0 + akk);
    };

    int w    = tid >> 6;
    int lane = tid & 63;
    int wm = (w & 1) * 16;           // wave row offset (0/16)
    int wn = (w >> 1) * 64;          // wave col offset (0/64)
    int lr = lane & 15, lq = lane >> 4;

    f32x4 acc[4];
#pragma unroll
    for (int e = 0; e < 4; ++e) acc[e] = (f32x4){0.f, 0.f, 0.f, 0.f};

    loadAB(0);
    for (int k0 = 0; k0 < HID_; k0 += 64) {
        __syncthreads();
        *(bf16x8*)&As[arow][akk] = pA;
#pragma unroll
        for (int e = 0; e < 4; ++e)
            *(bf16x8*)&Bs[arow + e * 32][akk] = pB[e];
        __syncthreads();
        if (k0 + 64 < HID_) loadAB(k0 + 64);
#pragma unroll
        for (int ks = 0; ks < 2; ++ks) {
            int kb = ks * 32 + lq * 8;
            bf16x8 a = *(bf16x8*)&As[wm + lr][kb];
#pragma unroll
            for (int nf = 0; nf < 4; ++nf) {
                bf16x8 bb = *(bf16x8*)&Bs[wn + nf * 16 + lr][kb];
                acc[nf] = __builtin_amdgcn_mfma_f32_16x16x32_bf16(a, bb, acc[nf], 0, 0, 0);
            }
        }
    }

    int grow = m0 + wm + lq * 4;
#pragma unroll
    for (int nf = 0; nf < 4; ++nf) {
        int col = wn + nf * 16 + lr;
        if (col < REL_) {
            float bias = b2[col];
#pragma unroll
            for (int r = 0; r < 4; ++r)
                out[(size_t)(grow + r) * REL_ + col] = acc[nf][r] + bias;
        }
    }
}

// ---------------------------------------------------------------------------
extern "C" void kernel_launch(void* const* d_in, const int* in_sizes, int n_in,
                              void* d_out, int out_size, void* d_ws, size_t ws_size,
                              hipStream_t stream)
{
    const float* sr    = (const float*)d_in[0];
    const int*   spans = (const int*)  d_in[1];
    const int*   vidx  = (const int*)  d_in[3];
    const int*   vmask = (const int*)  d_in[4];
    const int*   ht    = (const int*)  d_in[5];
    const int*   dht   = (const int*)  d_in[7];
    const int*   dth   = (const int*)  d_in[8];
    const float* dis   = (const float*)d_in[9];
    const float* W1    = (const float*)d_in[10];
    const float* W2    = (const float*)d_in[11];
    const float* b2    = (const float*)d_in[12];
    float* out = (float*)d_out;

    // ws: span_emb f32 | vembB bf16 | W1T bf16 | W2T bf16 | hiddenB bf16 (~24 MB)
    float*    span_emb = (float*)d_ws;                                  // 4096*768 f32
    ushort_t* vembB    = (ushort_t*)(span_emb + (size_t)B_ * NS_ * D_); // 2048*768
    ushort_t* W1T      = vembB + (size_t)B_ * V_ * D_;                  // 384*2368
    ushort_t* W2T      = W1T + (size_t)HID_ * KP_;                      // 128*384
    ushort_t* hiddenB  = W2T + (size_t)N2P_ * HID_;                     // 8192*384

    span_kernel<<<B_ * NS_, 256, 0, stream>>>(sr, spans, span_emb);
    vertex_kernel<<<B_ * V_, 256, 0, stream>>>(span_emb, vidx, vmask, vembB);
    wconv_kernel<<<156, 384, 0, stream>>>(W1, W2, W1T, W2T);

    dim3 g1((B_ * R_) / 64, HID_ / 64);        // 128 x 6 = 768 blocks
    gemm1_kernel<<<g1, 256, 0, stream>>>(vembB, ht, dht, dth, dis, W1T, hiddenB);

    gemm2_kernel<<<(B_ * R_) / 32, 256, 0, stream>>>(hiddenB, W2T, b2, out);
}